// Round 1
// baseline (1978.715 us; speedup 1.0000x reference)
//
#include <hip/hip_runtime.h>
#include <cmath>

namespace {
constexpr int kB  = 16;
constexpr int kNH = 8;
constexpr int kNG = 1024;   // 32*32 groups
constexpr float kScale = 0.17677669529663687f;  // 32^-0.5
}

typedef short  bf16x8 __attribute__((ext_vector_type(8)));
typedef short  bf16x4 __attribute__((ext_vector_type(4)));
typedef float  f32x4  __attribute__((ext_vector_type(4)));

__device__ __forceinline__ unsigned short f2b(float f) {
  unsigned int u = __builtin_bit_cast(unsigned int, f);
  u += 0x7fffu + ((u >> 16) & 1u);          // RNE
  return (unsigned short)(u >> 16);
}
__device__ __forceinline__ float b2f(unsigned short h) {
  unsigned int u = ((unsigned int)h) << 16;
  return __builtin_bit_cast(float, u);
}

// ---------------- k_wcvt: w_qkv (768x256) -> bf16; w_out (256x256) -> bf16 hi+lo ----
__global__ void __launch_bounds__(256) k_wcvt(const float* __restrict__ w_qkv,
                                              const float* __restrict__ w_out,
                                              unsigned short* __restrict__ wb,
                                              unsigned short* __restrict__ w_hi,
                                              unsigned short* __restrict__ w_lo) {
  int i = blockIdx.x * 256 + threadIdx.x;   // grid 1024 -> 262144
  if (i < 196608) {
    wb[i] = f2b(w_qkv[i]);
  } else {
    int k = i - 196608;                     // < 65536
    float v = w_out[k];
    unsigned short h = f2b(v);
    w_hi[k] = h;
    w_lo[k] = f2b(v - b2f(h));              // hi+lo ~ fp32-accurate weight
  }
}

// ---------------- k1: fused MFMA qkv-GEMM + 10-token attention + LN/GELU --------
// Block: 2 groups. GEMM D[m=32 token-rows (2 grps x 16)][n=768 o] = Xg * W^T, K=256.
// m-row layout per group: 0 = group token, 1..9 = pixels, 10..15 = zero (masked).
// LDS (shorts): qk_l[32][520] (aliased by A_l[32][264] in phase 1),
//               vt[2*256][40] (V^T, j-slots 16..31 zeroed), pl[4][16][40].
__global__ void __launch_bounds__(256, 2)
k_qkv_attn(const float* __restrict__ x, const unsigned short* __restrict__ w_bf,
           const float* __restrict__ gtok, const float* __restrict__ ln_g,
           const float* __restrict__ ln_b, unsigned short* __restrict__ t_b,
           unsigned short* __restrict__ gf_b) {
  __shared__ __align__(16) short smem[39680];   // 79360 B
  short* qk_l = smem;            // [32][520]   (phase2) / A_l [32][264] (phase1)
  short* vt   = smem + 16640;    // [512][40]
  short* pl   = smem + 37120;    // [4][16][40]

  const int tid = threadIdx.x;
  // XCD-aware bijective swizzle (8192 % 8 == 0): consecutive logical pairs
  // (adjacent gy windows sharing x cachelines) land on the same XCD's L2.
  const int bid0 = blockIdx.x;           // 16 b * 512 pairs
  const int lg  = (bid0 & 7) * 1024 + (bid0 >> 3);
  const int b   = lg >> 9;
  const int n0  = (lg & 511) * 2;
  const int wv  = tid >> 6;
  const int lane = tid & 63;
  const int ln  = lane & 15;
  const int qq  = lane >> 4;
  const int n0w = wv * 192;

  // ---- stage A (gathered x window + token row, zero pad rows) ----
  for (int r = 0; r < 32; ++r) {
    int i = r * 256 + tid;
    int m = i & 31, c = i >> 5;
    int m16 = m & 15;
    float val = 0.f;
    if (m16 == 0) {
      val = gtok[c];
    } else if (m16 <= 9) {
      int pix = m16 - 1;
      int n = n0 + (m >> 4);
      int gx = n >> 5, gy = n & 31;
      int gi = pix / 3, gj = pix - gi * 3;
      val = x[((size_t)(b * 256 + c) * 96 + gx * 3 + gi) * 96 + gy * 3 + gj];
    }
    qk_l[m * 264 + c] = (short)f2b(val);   // A_l alias
  }
  __syncthreads();

  // ---- K-loop: D[m][o] = sum_c A[m][c] * W[o][c] ----
  f32x4 acc[2][12];
#pragma unroll
  for (int mf = 0; mf < 2; ++mf)
#pragma unroll
    for (int nf = 0; nf < 12; ++nf) acc[mf][nf] = {0.f, 0.f, 0.f, 0.f};

  for (int ks = 0; ks < 8; ++ks) {
    bf16x8 a0 = *(const bf16x8*)&qk_l[ln * 264 + ks * 32 + qq * 8];
    bf16x8 a1 = *(const bf16x8*)&qk_l[(16 + ln) * 264 + ks * 32 + qq * 8];
#pragma unroll
    for (int nf = 0; nf < 12; ++nf) {
      bf16x8 bw = *(const bf16x8*)&w_bf[(size_t)(n0w + nf * 16 + ln) * 256 + ks * 32 + qq * 8];
      acc[0][nf] = __builtin_amdgcn_mfma_f32_16x16x32_bf16(a0, bw, acc[0][nf], 0, 0, 0);
      acc[1][nf] = __builtin_amdgcn_mfma_f32_16x16x32_bf16(a1, bw, acc[1][nf], 0, 0, 0);
    }
  }
  __syncthreads();   // A_l dead

  // ---- scatter D -> qk_l (q,k) and vt (v transposed), plus zero pads ----
#pragma unroll
  for (int mf = 0; mf < 2; ++mf)
#pragma unroll
    for (int nf = 0; nf < 12; ++nf) {
      int o = n0w + nf * 16 + ln;
#pragma unroll
      for (int r = 0; r < 4; ++r) {
        short hv = (short)f2b(acc[mf][nf][r]);
        int ml = qq * 4 + r;
        if (o < 512) qk_l[(mf * 16 + ml) * 520 + o] = hv;
        else         vt[((mf << 8) + (o - 512)) * 40 + ml] = hv;
      }
    }
  for (int t = tid; t < 8192; t += 256) vt[(t >> 4) * 40 + 16 + (t & 15)] = 0;
  for (int t = tid; t < 1024; t += 256)
    pl[(t >> 8) * 640 + ((t & 255) >> 4) * 40 + 16 + (t & 15)] = 0;
  __syncthreads();

  // ---- per (group, head) attention: 4 tasks per wave ----
  for (int tt = 0; tt < 4; ++tt) {
    int task = wv * 4 + tt;
    int grp = task >> 3, hh = task & 7;
    int n = n0 + grp;

    bf16x8 aq = *(const bf16x8*)&qk_l[(grp * 16 + ln) * 520 + hh * 32 + qq * 8];
    bf16x8 bk = *(const bf16x8*)&qk_l[(grp * 16 + ln) * 520 + 256 + hh * 32 + qq * 8];
    f32x4 z = {0.f, 0.f, 0.f, 0.f};
    f32x4 s = __builtin_amdgcn_mfma_f32_16x16x32_bf16(aq, bk, z, 0, 0, 0);

    float pr[4], sm[4];
#pragma unroll
    for (int r = 0; r < 4; ++r) {
      float sv = s[r] * kScale;
      if (ln >= 10) sv = -1e30f;
      float mx = sv;
#pragma unroll
      for (int d = 1; d < 16; d <<= 1) mx = fmaxf(mx, __shfl_xor(mx, d));
      pr[r] = __expf(sv - mx);
      float t2 = pr[r];
#pragma unroll
      for (int d = 1; d < 16; d <<= 1) t2 += __shfl_xor(t2, d);
      sm[r] = t2;
    }
#pragma unroll
    for (int r = 0; r < 4; ++r)
      pl[wv * 640 + (qq * 4 + r) * 40 + ln] = (short)f2b(pr[r]);

    bf16x8 ap = *(const bf16x8*)&pl[wv * 640 + ln * 40 + qq * 8];
    bf16x8 v0 = *(const bf16x8*)&vt[((grp << 8) + hh * 32 + ln) * 40 + qq * 8];
    bf16x8 v1 = *(const bf16x8*)&vt[((grp << 8) + hh * 32 + 16 + ln) * 40 + qq * 8];
    f32x4 o0 = __builtin_amdgcn_mfma_f32_16x16x32_bf16(ap, v0, z, 0, 0, 0);
    f32x4 o1 = __builtin_amdgcn_mfma_f32_16x16x32_bf16(ap, v1, z, 0, 0, 0);

    if (qq == 0) {  // row 0 = group token -> LN + GELU -> t
      float inv0 = 1.f / sm[0];
      float va = o0[0] * inv0, vb = o1[0] * inv0;
      float ssum = va + vb;
#pragma unroll
      for (int d = 1; d < 16; d <<= 1) ssum += __shfl_xor(ssum, d);
      float mu = ssum * (1.f / 32.f);
      float dva = va - mu, dvb = vb - mu;
      float vsum = dva * dva + dvb * dvb;
#pragma unroll
      for (int d = 1; d < 16; d <<= 1) vsum += __shfl_xor(vsum, d);
      float ri = rsqrtf(vsum * (1.f / 32.f) + 1e-5f);
      float g0 = dva * ri * ln_g[ln] + ln_b[ln];
      float g1 = dvb * ri * ln_g[16 + ln] + ln_b[16 + ln];
      float e0 = 0.5f * g0 * (1.f + erff(g0 * 0.70710678118654752f));
      float e1 = 0.5f * g1 * (1.f + erff(g1 * 0.70710678118654752f));
      size_t tb = ((size_t)(b * 1024 + n)) * 256 + hh * 32 + ln;
      t_b[tb] = f2b(e0);
      t_b[tb + 16] = f2b(e1);
    }
#pragma unroll
    for (int r = 0; r < 4; ++r) {
      int i = qq * 4 + r;
      if (i >= 1 && i <= 9) {
        float inv = 1.f / sm[r];
        size_t base = ((size_t)((b * 8 + hh) * 1024) + n) * 288 + (i - 1) * 32 + ln;
        gf_b[base] = f2b(o0[r] * inv);
        gf_b[base + 16] = f2b(o1[r] * inv);
      }
    }
  }
}

// ---------------- k2: qk = w_qk(512x256) @ t + b_qk -> wq_b (scaled), wk_b ------
__global__ void __launch_bounds__(256, 2)
k_qk(const unsigned short* __restrict__ t_b, const float* __restrict__ w_qk,
     const float* __restrict__ b_qk, unsigned short* __restrict__ wq_b,
     unsigned short* __restrict__ wk_b) {
  __shared__ float t_l[128][33];
  __shared__ float w_l[64][33];
  int tid = threadIdx.x;
  int bid = blockIdx.x;       // 16 b * 8 h * 8 ntiles
  int b = bid >> 6;
  int h = (bid >> 3) & 7;
  int nt = bid & 7;
  int n_base = nt * 128;
  int te = tid & 15, tn = tid >> 4;
  float accq[4][8] = {};
  for (int c0 = 0; c0 < 256; c0 += 32) {
    for (int i = 0; i < 16; ++i) {
      int nl = i * 8 + (tid >> 5);
      t_l[nl][tid & 31] = b2f(t_b[((size_t)(b * kNG) + n_base + nl) * 256 + c0 + (tid & 31)]);
    }
    for (int i = 0; i < 8; ++i) {
      int e = i * 8 + (tid >> 5);
      w_l[e][tid & 31] = w_qk[(size_t)(h * 64 + e) * 256 + c0 + (tid & 31)];
    }
    __syncthreads();
    for (int cc = 0; cc < 32; ++cc) {
      float wvv[4], tvv[8];
#pragma unroll
      for (int i = 0; i < 4; ++i) wvv[i] = w_l[te + 16 * i][cc];
#pragma unroll
      for (int j = 0; j < 8; ++j) tvv[j] = t_l[tn + 16 * j][cc];
#pragma unroll
      for (int i = 0; i < 4; ++i)
#pragma unroll
        for (int j = 0; j < 8; ++j) accq[i][j] += wvv[i] * tvv[j];
    }
    __syncthreads();
  }
#pragma unroll
  for (int i = 0; i < 4; ++i) {
    int e = te + 16 * i;
    float bias = b_qk[h * 64 + e];
#pragma unroll
    for (int j = 0; j < 8; ++j) {
      int n = n_base + tn + 16 * j;
      float v = accq[i][j] + bias;
      size_t idx = (((size_t)b * kNH + h) * kNG + n) * 32;
      if (e < 32) wq_b[idx + e] = f2b(v * kScale);
      else        wk_b[idx + (e - 32)] = f2b(v);
    }
  }
}

// ---------------- k3: MFMA flash attention, V = gf (288 cols), agg bf16 ---------
// Block: (bh, 64-row q-tile). Waves replicate QK/softmax, split 288 d-cols (80 each).
// vt uses a k-block XOR swizzle (col8 ^= (d>>2)&3) to break the 32-way bank
// conflict of the d-major transpose writes (bank stride was 16 -> 2 banks/wave).
__global__ void __launch_bounds__(256, 2)
k_flash(const unsigned short* __restrict__ wq_b, const unsigned short* __restrict__ wk_b,
        const unsigned short* __restrict__ gf_b, unsigned short* __restrict__ agg_b) {
  __shared__ __align__(16) short smem[24320];
  short* k_l = smem;             // [32][40]
  short* vt  = smem + 1280;      // [320][40]  (rows >=288 garbage, cols masked at store)
  short* pl  = smem + 14080;     // [4][64][40]

  const int tid = threadIdx.x;
  // XCD-aware swizzle (2048 % 8 == 0): all 16 q-tiles of a bh on one XCD,
  // qt-consecutive in launch order -> K/V tiles served from that XCD's L2.
  const int bid0 = blockIdx.x;   // 128 bh * 16 qtiles
  const int xcd = bid0 & 7;
  const int s   = bid0 >> 3;                 // 0..255 per-XCD sequence
  const int bh  = xcd + 8 * (s >> 4);
  const int qt  = s & 15;
  const int wv = tid >> 6;
  const int lane = tid & 63;
  const int ln = lane & 15;
  const int qq = lane >> 4;
  const int d0 = wv * 80;

  bf16x8 aq[4];
#pragma unroll
  for (int mf = 0; mf < 4; ++mf)
    aq[mf] = *(const bf16x8*)&wq_b[(size_t)(bh * 1024 + qt * 64 + mf * 16 + ln) * 32 + qq * 8];

  f32x4 accv[4][5];
  float mrow[4][4], lrow[4][4];
#pragma unroll
  for (int mf = 0; mf < 4; ++mf) {
#pragma unroll
    for (int nf = 0; nf < 5; ++nf) accv[mf][nf] = {0.f, 0.f, 0.f, 0.f};
#pragma unroll
    for (int r = 0; r < 4; ++r) { mrow[mf][r] = -1e30f; lrow[mf][r] = 0.f; }
  }

  for (int kt = 0; kt < 32; ++kt) {
    { // stage K tile [32 kc][32 d]
      int kc = tid >> 3, dd = (tid & 7) * 4;
      bf16x4 kv = *(const bf16x4*)&wk_b[(size_t)(bh * 1024 + kt * 32 + kc) * 32 + dd];
      *(bf16x4*)&k_l[kc * 40 + dd] = kv;
    }
#pragma unroll
    for (int r = 0; r < 9; ++r) {  // stage V^T: vt[d][kc], XOR-swizzled k-blocks
      int i = r * 256 + tid;
      int kc = i / 72, jj = i - kc * 72;
      int d4 = jj * 4;
      bf16x4 g4 = *(const bf16x4*)&gf_b[(size_t)(bh * 1024 + kt * 32 + kc) * 288 + d4];
      int sw = (((kc >> 3) ^ (jj & 3)) << 3) + (kc & 7);
#pragma unroll
      for (int xch = 0; xch < 4; ++xch) vt[(d4 + xch) * 40 + sw] = g4[xch];
    }
    __syncthreads();

    // QK
    f32x4 s4[4][2];
    f32x4 z = {0.f, 0.f, 0.f, 0.f};
    __builtin_amdgcn_s_setprio(1);
#pragma unroll
    for (int nf2 = 0; nf2 < 2; ++nf2) {
      bf16x8 kf = *(const bf16x8*)&k_l[(nf2 * 16 + ln) * 40 + qq * 8];
#pragma unroll
      for (int mf = 0; mf < 4; ++mf)
        s4[mf][nf2] = __builtin_amdgcn_mfma_f32_16x16x32_bf16(aq[mf], kf, z, 0, 0, 0);
    }
    __builtin_amdgcn_s_setprio(0);
    // online softmax per row
#pragma unroll
    for (int mf = 0; mf < 4; ++mf)
#pragma unroll
      for (int r = 0; r < 4; ++r) {
        float s0 = s4[mf][0][r], s1 = s4[mf][1][r];
        float tm = fmaxf(s0, s1);
#pragma unroll
        for (int d = 1; d < 16; d <<= 1) tm = fmaxf(tm, __shfl_xor(tm, d));
        float nm = fmaxf(mrow[mf][r], tm);
        float al = __expf(mrow[mf][r] - nm);
        mrow[mf][r] = nm;
        float p0 = __expf(s0 - nm), p1 = __expf(s1 - nm);
        float ts = p0 + p1;
#pragma unroll
        for (int d = 1; d < 16; d <<= 1) ts += __shfl_xor(ts, d);
        lrow[mf][r] = lrow[mf][r] * al + ts;
#pragma unroll
        for (int nf = 0; nf < 5; ++nf) accv[mf][nf][r] *= al;
        int row = mf * 16 + qq * 4 + r;
        pl[wv * 2560 + row * 40 + ln] = (short)f2b(p0);
        pl[wv * 2560 + row * 40 + 16 + ln] = (short)f2b(p1);
      }
    // PV
    bf16x8 ap[4];
#pragma unroll
    for (int mf = 0; mf < 4; ++mf)
      ap[mf] = *(const bf16x8*)&pl[wv * 2560 + (mf * 16 + ln) * 40 + qq * 8];
    __builtin_amdgcn_s_setprio(1);
#pragma unroll
    for (int nf = 0; nf < 5; ++nf) {
      int dmy = d0 + nf * 16 + ln;
      bf16x8 vf = *(const bf16x8*)&vt[dmy * 40 + ((qq ^ ((dmy >> 2) & 3)) << 3)];
#pragma unroll
      for (int mf = 0; mf < 4; ++mf)
        accv[mf][nf] = __builtin_amdgcn_mfma_f32_16x16x32_bf16(ap[mf], vf, accv[mf][nf], 0, 0, 0);
    }
    __builtin_amdgcn_s_setprio(0);
    __syncthreads();
  }
  // epilogue
#pragma unroll
  for (int mf = 0; mf < 4; ++mf)
#pragma unroll
    for (int nf = 0; nf < 5; ++nf) {
      int d = d0 + nf * 16 + ln;
      if (d < 288) {
#pragma unroll
        for (int r = 0; r < 4; ++r) {
          int row = qt * 64 + mf * 16 + qq * 4 + r;
          agg_b[((size_t)(bh * 1024) + row) * 288 + d] = f2b(accv[mf][nf][r] / lrow[mf][r]);
        }
      }
    }
}

// ---------------- k4: out = w_out(256x256) @ fmap + b_out, MFMA version ----------
// Block: (b, 64-pixel tile). Wave w owns o-rows [w*64, w*64+64). K = 256 (h*32+dd).
// A = w_out split hi+lo bf16 (near-fp32 weight); B = agg_b rows gathered direct
// from global (16 rows x 64B full cachelines per frag load). No LDS.
__global__ void __launch_bounds__(256, 2)
k_out(const unsigned short* __restrict__ agg_b,
      const unsigned short* __restrict__ w_hi, const unsigned short* __restrict__ w_lo,
      const float* __restrict__ b_out, float* __restrict__ out) {
  const int tid = threadIdx.x;
  const int bid = blockIdx.x;        // 16 b * 144 ptiles
  const int b = bid / 144;
  const int pt = bid - b * 144;
  const int p_base = pt * 64;
  const int wv = tid >> 6, lane = tid & 63, ln = lane & 15, qq = lane >> 4;
  const int obase = wv * 64;

  // per-lane B row bases for the 4 nf pixel-subtiles
  size_t vbase[4];
#pragma unroll
  for (int nf = 0; nf < 4; ++nf) {
    int p = p_base + nf * 16 + ln;
    int hh2 = p / 96, ww2 = p - hh2 * 96;
    int xg = hh2 / 3, gi = hh2 - xg * 3;
    int yg = ww2 / 3, gj = ww2 - yg * 3;
    int n = xg * 32 + yg, w = gi * 3 + gj;
    vbase[nf] = ((size_t)b * 8 * 1024 + n) * 288 + w * 32 + qq * 8;
  }

  f32x4 acc[4][4];
#pragma unroll
  for (int mf = 0; mf < 4; ++mf)
#pragma unroll
    for (int nf = 0; nf < 4; ++nf) acc[mf][nf] = {0.f, 0.f, 0.f, 0.f};

  for (int ks = 0; ks < 8; ++ks) {   // ks == h
    bf16x8 bfr[4];
#pragma unroll
    for (int nf = 0; nf < 4; ++nf)
      bfr[nf] = *(const bf16x8*)&agg_b[vbase[nf] + (size_t)ks * 294912];  // 1024*288
#pragma unroll
    for (int mf = 0; mf < 4; ++mf) {
      int o = obase + mf * 16 + ln;
      bf16x8 ah = *(const bf16x8*)&w_hi[o * 256 + ks * 32 + qq * 8];
      bf16x8 al = *(const bf16x8*)&w_lo[o * 256 + ks * 32 + qq * 8];
#pragma unroll
      for (int nf = 0; nf < 4; ++nf) {
        acc[mf][nf] = __builtin_amdgcn_mfma_f32_16x16x32_bf16(ah, bfr[nf], acc[mf][nf], 0, 0, 0);
        acc[mf][nf] = __builtin_amdgcn_mfma_f32_16x16x32_bf16(al, bfr[nf], acc[mf][nf], 0, 0, 0);
      }
    }
  }
  // epilogue: D col = p (ln), row = o (qq*4+r); 16-lane rows are 64B contiguous
#pragma unroll
  for (int mf = 0; mf < 4; ++mf) {
#pragma unroll
    for (int r = 0; r < 4; ++r) {
      int o = obase + mf * 16 + qq * 4 + r;
      float bias = b_out[o];
#pragma unroll
      for (int nf = 0; nf < 4; ++nf) {
        int p = p_base + nf * 16 + ln;
        out[((size_t)b * 256 + o) * 9216 + p] = acc[mf][nf][r] + bias;
      }
    }
  }
}

extern "C" void kernel_launch(void* const* d_in, const int* in_sizes, int n_in,
                              void* d_out, int out_size, void* d_ws, size_t ws_size,
                              hipStream_t stream) {
  const float* x     = (const float*)d_in[0];
  const float* w_qkv = (const float*)d_in[1];
  const float* gtok  = (const float*)d_in[2];
  const float* ln_g  = (const float*)d_in[3];
  const float* ln_b  = (const float*)d_in[4];
  const float* w_qk  = (const float*)d_in[5];
  const float* b_qk  = (const float*)d_in[6];
  const float* w_out = (const float*)d_in[7];
  const float* b_out = (const float*)d_in[8];
  float* out = (float*)d_out;

  unsigned short* ws   = (unsigned short*)d_ws;
  unsigned short* w_bf = ws;                        // 196,608
  unsigned short* t_b  = w_bf + 196608;             // 16*1024*256   = 4,194,304
  unsigned short* wq_b = t_b + 4194304;             // 16*8*1024*32  = 4,194,304
  unsigned short* wk_b = wq_b + 4194304;            // 4,194,304
  unsigned short* gf_b = wk_b + 4194304;            // 16*8*1024*288 = 37,748,736
  unsigned short* agg_b = gf_b + 37748736;          // 37,748,736
  unsigned short* w_hi = agg_b + 37748736;          // 65,536
  unsigned short* w_lo = w_hi + 65536;              // 65,536
  // total ~88.4M shorts = 176.8 MB

  k_wcvt<<<1024, 256, 0, stream>>>(w_qkv, w_out, w_bf, w_hi, w_lo);
  k_qkv_attn<<<8192, 256, 0, stream>>>(x, w_bf, gtok, ln_g, ln_b, t_b, gf_b);
  k_qk<<<1024, 256, 0, stream>>>(t_b, w_qk, b_qk, wq_b, wk_b);
  k_flash<<<2048, 256, 0, stream>>>(wq_b, wk_b, gf_b, agg_b);
  k_out<<<2304, 256, 0, stream>>>(agg_b, w_hi, w_lo, b_out, out);
}

// Round 2
// 1314.453 us; speedup vs baseline: 1.5054x; 1.5054x over previous
//
#include <hip/hip_runtime.h>
#include <cmath>

namespace {
constexpr int kB  = 16;
constexpr int kNH = 8;
constexpr int kNG = 1024;   // 32*32 groups
constexpr float kScale = 0.17677669529663687f;  // 32^-0.5
}

typedef short  bf16x8 __attribute__((ext_vector_type(8)));
typedef short  bf16x4 __attribute__((ext_vector_type(4)));
typedef float  f32x4  __attribute__((ext_vector_type(4)));

__device__ __forceinline__ unsigned short f2b(float f) {
  unsigned int u = __builtin_bit_cast(unsigned int, f);
  u += 0x7fffu + ((u >> 16) & 1u);          // RNE
  return (unsigned short)(u >> 16);
}
__device__ __forceinline__ float b2f(unsigned short h) {
  unsigned int u = ((unsigned int)h) << 16;
  return __builtin_bit_cast(float, u);
}

// ---------------- k_wcvt: w_qkv (768x256) -> bf16; w_out (256x256) -> bf16 hi+lo ----
__global__ void __launch_bounds__(256) k_wcvt(const float* __restrict__ w_qkv,
                                              const float* __restrict__ w_out,
                                              unsigned short* __restrict__ wb,
                                              unsigned short* __restrict__ w_hi,
                                              unsigned short* __restrict__ w_lo) {
  int i = blockIdx.x * 256 + threadIdx.x;   // grid 1024 -> 262144
  if (i < 196608) {
    wb[i] = f2b(w_qkv[i]);
  } else {
    int k = i - 196608;                     // < 65536
    float v = w_out[k];
    unsigned short h = f2b(v);
    w_hi[k] = h;
    w_lo[k] = f2b(v - b2f(h));              // hi+lo ~ fp32-accurate weight
  }
}

// ---------------- k1: fused MFMA qkv-GEMM + 10-token attention + LN/GELU --------
// Block: 2 groups. GEMM D[m=32 token-rows (2 grps x 16)][n=768 o] = Xg * W^T, K=256.
// gf is now written TRANSPOSED: gf_t[bh][d=288][n=1024] so k_flash can stage V^T
// with vectorized conflict-free LDS writes.
__global__ void __launch_bounds__(256, 2)
k_qkv_attn(const float* __restrict__ x, const unsigned short* __restrict__ w_bf,
           const float* __restrict__ gtok, const float* __restrict__ ln_g,
           const float* __restrict__ ln_b, unsigned short* __restrict__ t_b,
           unsigned short* __restrict__ gf_t) {
  __shared__ __align__(16) short smem[39680];   // 79360 B
  short* qk_l = smem;            // [32][520]   (phase2) / A_l [32][264] (phase1)
  short* vt   = smem + 16640;    // [512][40]
  short* pl   = smem + 37120;    // [4][16][40]

  const int tid = threadIdx.x;
  // XCD-aware bijective swizzle (8192 % 8 == 0): consecutive logical pairs
  // land on the same XCD -> x cacheline sharing + gf_t line completion in L2.
  const int bid0 = blockIdx.x;           // 16 b * 512 pairs
  const int lg  = (bid0 & 7) * 1024 + (bid0 >> 3);
  const int b   = lg >> 9;
  const int n0  = (lg & 511) * 2;
  const int wv  = tid >> 6;
  const int lane = tid & 63;
  const int ln  = lane & 15;
  const int qq  = lane >> 4;
  const int n0w = wv * 192;

  // ---- stage A: per-lane base pointer is loop-invariant (m = tid&31 fixed);
  //      batch loads 16-deep into registers to hide gather latency ----
  {
    const int m   = tid & 31;
    const int cw  = tid >> 5;       // c = r*8 + cw, r = 0..31
    const int m16 = m & 15;
    const float* srcp = nullptr;
    int strd = 0;
    if (m16 == 0) {
      srcp = gtok + cw; strd = 8;
    } else if (m16 <= 9) {
      int pix = m16 - 1;
      int n = n0 + (m >> 4);
      int gx = n >> 5, gy = n & 31;
      int gi = pix / 3, gj = pix - gi * 3;
      srcp = x + ((size_t)(b * 256 + cw) * 96 + gx * 3 + gi) * 96 + gy * 3 + gj;
      strd = 8 * 9216;
    }
    float vv[16];
#pragma unroll
    for (int half = 0; half < 2; ++half) {
#pragma unroll
      for (int r = 0; r < 16; ++r)
        vv[r] = srcp ? srcp[(size_t)(half * 16 + r) * strd] : 0.f;
#pragma unroll
      for (int r = 0; r < 16; ++r)
        qk_l[m * 264 + (half * 16 + r) * 8 + cw] = (short)f2b(vv[r]);
    }
  }
  __syncthreads();

  // ---- K-loop: D[m][o] = sum_c A[m][c] * W[o][c] ----
  f32x4 acc[2][12];
#pragma unroll
  for (int mf = 0; mf < 2; ++mf)
#pragma unroll
    for (int nf = 0; nf < 12; ++nf) acc[mf][nf] = {0.f, 0.f, 0.f, 0.f};

  for (int ks = 0; ks < 8; ++ks) {
    bf16x8 a0 = *(const bf16x8*)&qk_l[ln * 264 + ks * 32 + qq * 8];
    bf16x8 a1 = *(const bf16x8*)&qk_l[(16 + ln) * 264 + ks * 32 + qq * 8];
#pragma unroll
    for (int nf = 0; nf < 12; ++nf) {
      bf16x8 bw = *(const bf16x8*)&w_bf[(size_t)(n0w + nf * 16 + ln) * 256 + ks * 32 + qq * 8];
      acc[0][nf] = __builtin_amdgcn_mfma_f32_16x16x32_bf16(a0, bw, acc[0][nf], 0, 0, 0);
      acc[1][nf] = __builtin_amdgcn_mfma_f32_16x16x32_bf16(a1, bw, acc[1][nf], 0, 0, 0);
    }
  }
  __syncthreads();   // A_l dead

  // ---- scatter D -> qk_l (q,k) and vt (v transposed), plus zero pads ----
#pragma unroll
  for (int mf = 0; mf < 2; ++mf)
#pragma unroll
    for (int nf = 0; nf < 12; ++nf) {
      int o = n0w + nf * 16 + ln;
#pragma unroll
      for (int r = 0; r < 4; ++r) {
        short hv = (short)f2b(acc[mf][nf][r]);
        int ml = qq * 4 + r;
        if (o < 512) qk_l[(mf * 16 + ml) * 520 + o] = hv;
        else         vt[((mf << 8) + (o - 512)) * 40 + ml] = hv;
      }
    }
  for (int t = tid; t < 8192; t += 256) vt[(t >> 4) * 40 + 16 + (t & 15)] = 0;
  for (int t = tid; t < 1024; t += 256)
    pl[(t >> 8) * 640 + ((t & 255) >> 4) * 40 + 16 + (t & 15)] = 0;
  __syncthreads();

  // ---- per (group, head) attention: 4 tasks per wave ----
  for (int tt = 0; tt < 4; ++tt) {
    int task = wv * 4 + tt;
    int grp = task >> 3, hh = task & 7;
    int n = n0 + grp;

    bf16x8 aq = *(const bf16x8*)&qk_l[(grp * 16 + ln) * 520 + hh * 32 + qq * 8];
    bf16x8 bk = *(const bf16x8*)&qk_l[(grp * 16 + ln) * 520 + 256 + hh * 32 + qq * 8];
    f32x4 z = {0.f, 0.f, 0.f, 0.f};
    f32x4 s = __builtin_amdgcn_mfma_f32_16x16x32_bf16(aq, bk, z, 0, 0, 0);

    float pr[4], sm[4];
#pragma unroll
    for (int r = 0; r < 4; ++r) {
      float sv = s[r] * kScale;
      if (ln >= 10) sv = -1e30f;
      float mx = sv;
#pragma unroll
      for (int d = 1; d < 16; d <<= 1) mx = fmaxf(mx, __shfl_xor(mx, d));
      pr[r] = __expf(sv - mx);
      float t2 = pr[r];
#pragma unroll
      for (int d = 1; d < 16; d <<= 1) t2 += __shfl_xor(t2, d);
      sm[r] = t2;
    }
#pragma unroll
    for (int r = 0; r < 4; ++r)
      pl[wv * 640 + (qq * 4 + r) * 40 + ln] = (short)f2b(pr[r]);

    bf16x8 ap = *(const bf16x8*)&pl[wv * 640 + ln * 40 + qq * 8];
    bf16x8 v0 = *(const bf16x8*)&vt[((grp << 8) + hh * 32 + ln) * 40 + qq * 8];
    bf16x8 v1 = *(const bf16x8*)&vt[((grp << 8) + hh * 32 + 16 + ln) * 40 + qq * 8];
    f32x4 o0 = __builtin_amdgcn_mfma_f32_16x16x32_bf16(ap, v0, z, 0, 0, 0);
    f32x4 o1 = __builtin_amdgcn_mfma_f32_16x16x32_bf16(ap, v1, z, 0, 0, 0);

    if (qq == 0) {  // row 0 = group token -> LN + GELU -> t
      float inv0 = 1.f / sm[0];
      float va = o0[0] * inv0, vb = o1[0] * inv0;
      float ssum = va + vb;
#pragma unroll
      for (int d = 1; d < 16; d <<= 1) ssum += __shfl_xor(ssum, d);
      float mu = ssum * (1.f / 32.f);
      float dva = va - mu, dvb = vb - mu;
      float vsum = dva * dva + dvb * dvb;
#pragma unroll
      for (int d = 1; d < 16; d <<= 1) vsum += __shfl_xor(vsum, d);
      float ri = rsqrtf(vsum * (1.f / 32.f) + 1e-5f);
      float g0 = dva * ri * ln_g[ln] + ln_b[ln];
      float g1 = dvb * ri * ln_g[16 + ln] + ln_b[16 + ln];
      float e0 = 0.5f * g0 * (1.f + erff(g0 * 0.70710678118654752f));
      float e1 = 0.5f * g1 * (1.f + erff(g1 * 0.70710678118654752f));
      size_t tb = ((size_t)(b * 1024 + n)) * 256 + hh * 32 + ln;
      t_b[tb] = f2b(e0);
      t_b[tb + 16] = f2b(e1);
    }
    // transposed gf store: gf_t[(bh*288 + d)*1024 + n], d = (i-1)*32 + dd
#pragma unroll
    for (int r = 0; r < 4; ++r) {
      int i = qq * 4 + r;
      if (i >= 1 && i <= 9) {
        float inv = 1.f / sm[r];
        size_t base = ((size_t)((b * 8 + hh) * 288) + (i - 1) * 32 + ln) * 1024 + n;
        gf_t[base] = f2b(o0[r] * inv);
        gf_t[base + 16 * 1024] = f2b(o1[r] * inv);
      }
    }
  }
}

// ---------------- k2: qk = w_qk(512x256) @ t + b_qk -> wq_b (scaled), wk_b ------
__global__ void __launch_bounds__(256, 2)
k_qk(const unsigned short* __restrict__ t_b, const float* __restrict__ w_qk,
     const float* __restrict__ b_qk, unsigned short* __restrict__ wq_b,
     unsigned short* __restrict__ wk_b) {
  __shared__ float t_l[128][33];
  __shared__ float w_l[64][33];
  int tid = threadIdx.x;
  int bid = blockIdx.x;       // 16 b * 8 h * 8 ntiles
  int b = bid >> 6;
  int h = (bid >> 3) & 7;
  int nt = bid & 7;
  int n_base = nt * 128;
  int te = tid & 15, tn = tid >> 4;
  float accq[4][8] = {};
  for (int c0 = 0; c0 < 256; c0 += 32) {
    for (int i = 0; i < 16; ++i) {
      int nl = i * 8 + (tid >> 5);
      t_l[nl][tid & 31] = b2f(t_b[((size_t)(b * kNG) + n_base + nl) * 256 + c0 + (tid & 31)]);
    }
    for (int i = 0; i < 8; ++i) {
      int e = i * 8 + (tid >> 5);
      w_l[e][tid & 31] = w_qk[(size_t)(h * 64 + e) * 256 + c0 + (tid & 31)];
    }
    __syncthreads();
    for (int cc = 0; cc < 32; ++cc) {
      float wvv[4], tvv[8];
#pragma unroll
      for (int i = 0; i < 4; ++i) wvv[i] = w_l[te + 16 * i][cc];
#pragma unroll
      for (int j = 0; j < 8; ++j) tvv[j] = t_l[tn + 16 * j][cc];
#pragma unroll
      for (int i = 0; i < 4; ++i)
#pragma unroll
        for (int j = 0; j < 8; ++j) accq[i][j] += wvv[i] * tvv[j];
    }
    __syncthreads();
  }
#pragma unroll
  for (int i = 0; i < 4; ++i) {
    int e = te + 16 * i;
    float bias = b_qk[h * 64 + e];
#pragma unroll
    for (int j = 0; j < 8; ++j) {
      int n = n_base + tn + 16 * j;
      float v = accq[i][j] + bias;
      size_t idx = (((size_t)b * kNH + h) * kNG + n) * 32;
      if (e < 32) wq_b[idx + e] = f2b(v * kScale);
      else        wk_b[idx + (e - 32)] = f2b(v);
    }
  }
}

// ---------------- k3: MFMA flash attention over gf_t (pre-transposed V) ---------
// Block: (bh, 64-row q-tile). Wave w OWNS q-rows [16w,16w+16): does QK (K direct
// from global, L2-resident) + softmax for those rows only (no replication),
// publishes P / al / lrow via LDS; all waves rescale + PV their 80-d column slice.
// vt is row-major [d][j] with pitch 40 -> all accesses are b128 and bank-balanced.
__global__ void __launch_bounds__(256, 3)
k_flash(const unsigned short* __restrict__ wq_b, const unsigned short* __restrict__ wk_b,
        const unsigned short* __restrict__ gf_t, unsigned short* __restrict__ agg_b) {
  __shared__ __align__(16) short vt[12800];   // [320][40] V^T: vt[d][j]
  __shared__ __align__(16) short pl[2560];    // [64][40]  P
  __shared__ float al_l[64];
  __shared__ float lrow_l[64];

  const int tid = threadIdx.x;
  // XCD swizzle: all 16 q-tiles of a bh on one XCD, consecutive launch order.
  const int bid0 = blockIdx.x;   // 128 bh * 16 qtiles
  const int xcd = bid0 & 7;
  const int s   = bid0 >> 3;
  const int bh  = xcd + 8 * (s >> 4);
  const int qt  = s & 15;
  const int wv = tid >> 6;
  const int lane = tid & 63;
  const int ln = lane & 15;
  const int qq = lane >> 4;
  const int d0 = wv * 80;

  // own 16 q-rows
  bf16x8 aq = *(const bf16x8*)&wq_b[(size_t)(bh * 1024 + qt * 64 + wv * 16 + ln) * 32 + qq * 8];

  f32x4 accv[4][5];
  float mrow[4], lrow[4];
#pragma unroll
  for (int mf = 0; mf < 4; ++mf)
#pragma unroll
    for (int nf = 0; nf < 5; ++nf) accv[mf][nf] = {0.f, 0.f, 0.f, 0.f};
#pragma unroll
  for (int r = 0; r < 4; ++r) { mrow[r] = -1e30f; lrow[r] = 0.f; }

  // zero garbage d-rows 288..319 (read by wave 3's masked nf slots)
  for (int i = tid; i < 1280; i += 256) vt[11520 + i] = 0;

  for (int kt = 0; kt < 32; ++kt) {
    __syncthreads();              // prev PV done reading vt/pl
    // stage V^T tile: 288 d-rows x 32 j, b128 loads + b128 LDS writes
#pragma unroll
    for (int ii = 0; ii < 5; ++ii) {
      int i = ii * 256 + tid;
      if (i < 1152) {
        int d = i >> 2, c = (i & 3) * 8;
        bf16x8 g = *(const bf16x8*)&gf_t[((size_t)(bh * 288 + d)) * 1024 + kt * 32 + c];
        *(bf16x8*)&vt[d * 40 + c] = g;
      }
    }
    // QK for own rows, K straight from global (L2-hit; overlaps vt staging)
    f32x4 z = {0.f, 0.f, 0.f, 0.f};
    bf16x8 kf0 = *(const bf16x8*)&wk_b[(size_t)(bh * 1024 + kt * 32 + ln) * 32 + qq * 8];
    bf16x8 kf1 = *(const bf16x8*)&wk_b[(size_t)(bh * 1024 + kt * 32 + 16 + ln) * 32 + qq * 8];
    f32x4 s0v = __builtin_amdgcn_mfma_f32_16x16x32_bf16(aq, kf0, z, 0, 0, 0);
    f32x4 s1v = __builtin_amdgcn_mfma_f32_16x16x32_bf16(aq, kf1, z, 0, 0, 0);
    // online softmax, own 4 rows (per qq quadrant)
#pragma unroll
    for (int r = 0; r < 4; ++r) {
      float a0 = s0v[r], a1 = s1v[r];
      float tm = fmaxf(a0, a1);
#pragma unroll
      for (int d = 1; d < 16; d <<= 1) tm = fmaxf(tm, __shfl_xor(tm, d));
      float nm = fmaxf(mrow[r], tm);
      float al = __expf(mrow[r] - nm);
      mrow[r] = nm;
      float p0 = __expf(a0 - nm), p1 = __expf(a1 - nm);
      float ts = p0 + p1;
#pragma unroll
      for (int d = 1; d < 16; d <<= 1) ts += __shfl_xor(ts, d);
      lrow[r] = lrow[r] * al + ts;
      int row = wv * 16 + qq * 4 + r;
      pl[row * 40 + ln] = (short)f2b(p0);
      pl[row * 40 + 16 + ln] = (short)f2b(p1);
      if (ln == 0) al_l[row] = al;
    }
    __syncthreads();              // vt, pl, al ready
    // rescale all rows (al broadcast from LDS)
#pragma unroll
    for (int mf = 0; mf < 4; ++mf)
#pragma unroll
      for (int r = 0; r < 4; ++r) {
        float alv = al_l[mf * 16 + qq * 4 + r];
#pragma unroll
        for (int nf = 0; nf < 5; ++nf) accv[mf][nf][r] *= alv;
      }
    // PV: all 64 rows x own 80-d slice
    bf16x8 ap[4];
#pragma unroll
    for (int mf = 0; mf < 4; ++mf)
      ap[mf] = *(const bf16x8*)&pl[(mf * 16 + ln) * 40 + qq * 8];
    __builtin_amdgcn_s_setprio(1);
#pragma unroll
    for (int nf = 0; nf < 5; ++nf) {
      bf16x8 vf = *(const bf16x8*)&vt[(d0 + nf * 16 + ln) * 40 + qq * 8];
#pragma unroll
      for (int mf = 0; mf < 4; ++mf)
        accv[mf][nf] = __builtin_amdgcn_mfma_f32_16x16x32_bf16(ap[mf], vf, accv[mf][nf], 0, 0, 0);
    }
    __builtin_amdgcn_s_setprio(0);
  }
  // share lrow, then epilogue
#pragma unroll
  for (int r = 0; r < 4; ++r)
    if (ln == 0) lrow_l[wv * 16 + qq * 4 + r] = lrow[r];
  __syncthreads();
#pragma unroll
  for (int mf = 0; mf < 4; ++mf)
#pragma unroll
    for (int r = 0; r < 4; ++r) {
      float linv = 1.f / lrow_l[mf * 16 + qq * 4 + r];
      int row = qt * 64 + mf * 16 + qq * 4 + r;
#pragma unroll
      for (int nf = 0; nf < 5; ++nf) {
        int d = d0 + nf * 16 + ln;
        if (d < 288)
          agg_b[((size_t)(bh * 1024) + row) * 288 + d] = f2b(accv[mf][nf][r] * linv);
      }
    }
}

// ---------------- k4: out = w_out(256x256) @ fmap + b_out, MFMA version ----------
__global__ void __launch_bounds__(256, 2)
k_out(const unsigned short* __restrict__ agg_b,
      const unsigned short* __restrict__ w_hi, const unsigned short* __restrict__ w_lo,
      const float* __restrict__ b_out, float* __restrict__ out) {
  const int tid = threadIdx.x;
  const int bid = blockIdx.x;        // 16 b * 144 ptiles
  const int b = bid / 144;
  const int pt = bid - b * 144;
  const int p_base = pt * 64;
  const int wv = tid >> 6, lane = tid & 63, ln = lane & 15, qq = lane >> 4;
  const int obase = wv * 64;

  size_t vbase[4];
#pragma unroll
  for (int nf = 0; nf < 4; ++nf) {
    int p = p_base + nf * 16 + ln;
    int hh2 = p / 96, ww2 = p - hh2 * 96;
    int xg = hh2 / 3, gi = hh2 - xg * 3;
    int yg = ww2 / 3, gj = ww2 - yg * 3;
    int n = xg * 32 + yg, w = gi * 3 + gj;
    vbase[nf] = ((size_t)b * 8 * 1024 + n) * 288 + w * 32 + qq * 8;
  }

  f32x4 acc[4][4];
#pragma unroll
  for (int mf = 0; mf < 4; ++mf)
#pragma unroll
    for (int nf = 0; nf < 4; ++nf) acc[mf][nf] = {0.f, 0.f, 0.f, 0.f};

  for (int ks = 0; ks < 8; ++ks) {   // ks == h
    bf16x8 bfr[4];
#pragma unroll
    for (int nf = 0; nf < 4; ++nf)
      bfr[nf] = *(const bf16x8*)&agg_b[vbase[nf] + (size_t)ks * 294912];  // 1024*288
#pragma unroll
    for (int mf = 0; mf < 4; ++mf) {
      int o = obase + mf * 16 + ln;
      bf16x8 ah = *(const bf16x8*)&w_hi[o * 256 + ks * 32 + qq * 8];
      bf16x8 al = *(const bf16x8*)&w_lo[o * 256 + ks * 32 + qq * 8];
#pragma unroll
      for (int nf = 0; nf < 4; ++nf) {
        acc[mf][nf] = __builtin_amdgcn_mfma_f32_16x16x32_bf16(ah, bfr[nf], acc[mf][nf], 0, 0, 0);
        acc[mf][nf] = __builtin_amdgcn_mfma_f32_16x16x32_bf16(al, bfr[nf], acc[mf][nf], 0, 0, 0);
      }
    }
  }
#pragma unroll
  for (int mf = 0; mf < 4; ++mf) {
#pragma unroll
    for (int r = 0; r < 4; ++r) {
      int o = obase + mf * 16 + qq * 4 + r;
      float bias = b_out[o];
#pragma unroll
      for (int nf = 0; nf < 4; ++nf) {
        int p = p_base + nf * 16 + ln;
        out[((size_t)b * 256 + o) * 9216 + p] = acc[mf][nf][r] + bias;
      }
    }
  }
}

extern "C" void kernel_launch(void* const* d_in, const int* in_sizes, int n_in,
                              void* d_out, int out_size, void* d_ws, size_t ws_size,
                              hipStream_t stream) {
  const float* x     = (const float*)d_in[0];
  const float* w_qkv = (const float*)d_in[1];
  const float* gtok  = (const float*)d_in[2];
  const float* ln_g  = (const float*)d_in[3];
  const float* ln_b  = (const float*)d_in[4];
  const float* w_qk  = (const float*)d_in[5];
  const float* b_qk  = (const float*)d_in[6];
  const float* w_out = (const float*)d_in[7];
  const float* b_out = (const float*)d_in[8];
  float* out = (float*)d_out;

  unsigned short* ws   = (unsigned short*)d_ws;
  unsigned short* w_bf = ws;                        // 196,608
  unsigned short* t_b  = w_bf + 196608;             // 16*1024*256   = 4,194,304
  unsigned short* wq_b = t_b + 4194304;             // 16*8*1024*32  = 4,194,304
  unsigned short* wk_b = wq_b + 4194304;            // 4,194,304
  unsigned short* gf_t = wk_b + 4194304;            // 16*8*288*1024 = 37,748,736 (transposed)
  unsigned short* agg_b = gf_t + 37748736;          // 37,748,736
  unsigned short* w_hi = agg_b + 37748736;          // 65,536
  unsigned short* w_lo = w_hi + 65536;              // 65,536

  k_wcvt<<<1024, 256, 0, stream>>>(w_qkv, w_out, w_bf, w_hi, w_lo);
  k_qkv_attn<<<8192, 256, 0, stream>>>(x, w_bf, gtok, ln_g, ln_b, t_b, gf_t);
  k_qk<<<1024, 256, 0, stream>>>(t_b, w_qk, b_qk, wq_b, wk_b);
  k_flash<<<2048, 256, 0, stream>>>(wq_b, wk_b, gf_t, agg_b);
  k_out<<<2304, 256, 0, stream>>>(agg_b, w_hi, w_lo, b_out, out);
}

// Round 3
// 1256.199 us; speedup vs baseline: 1.5752x; 1.0464x over previous
//
#include <hip/hip_runtime.h>
#include <cmath>

namespace {
constexpr int kNH = 8;
constexpr int kNG = 1024;   // 32*32 groups
constexpr float kScale = 0.17677669529663687f;  // 32^-0.5
}

typedef short  bf16x8 __attribute__((ext_vector_type(8)));
typedef short  bf16x4 __attribute__((ext_vector_type(4)));
typedef float  f32x4  __attribute__((ext_vector_type(4)));

__device__ __forceinline__ unsigned short f2b(float f) {
  unsigned int u = __builtin_bit_cast(unsigned int, f);
  u += 0x7fffu + ((u >> 16) & 1u);          // RNE
  return (unsigned short)(u >> 16);
}
__device__ __forceinline__ float b2f(unsigned short h) {
  unsigned int u = ((unsigned int)h) << 16;
  return __builtin_bit_cast(float, u);
}
// vt column swizzle: spreads the d-major scalar writes across banks; XOR by
// multiples of 8 keeps the bf16x8 read groups intact and is bijective per row.
__device__ __forceinline__ int swc(int row, int col) {
  return col ^ (((row >> 3) & 3) << 3);
}

// ---------------- k_wcvt: w_qkv (768x256) -> bf16; w_out (256x256) -> bf16 hi+lo ----
__global__ void __launch_bounds__(256) k_wcvt(const float* __restrict__ w_qkv,
                                              const float* __restrict__ w_out,
                                              unsigned short* __restrict__ wb,
                                              unsigned short* __restrict__ w_hi,
                                              unsigned short* __restrict__ w_lo) {
  int i = blockIdx.x * 256 + threadIdx.x;   // grid 1024 -> 262144
  if (i < 196608) {
    wb[i] = f2b(w_qkv[i]);
  } else {
    int k = i - 196608;                     // < 65536
    float v = w_out[k];
    unsigned short h = f2b(v);
    w_hi[k] = h;
    w_lo[k] = f2b(v - b2f(h));              // hi+lo ~ fp32-accurate weight
  }
}

// ---------------- k_tok: qkv of the group token (shared by ALL windows) ---------
__global__ void __launch_bounds__(256) k_tok(const float* __restrict__ w_qkv,
                                             const float* __restrict__ gtok,
                                             unsigned short* __restrict__ tok_b) {
  int o = blockIdx.x * 256 + threadIdx.x;   // grid 3 -> 768
  if (o < 768) {
    float s = 0.f;
    for (int c = 0; c < 256; ++c) s += w_qkv[o * 256 + c] * gtok[c];
    tok_b[o] = f2b(s);
  }
}

// ---------------- k_xt: x[b][c][9216] fp32 -> xt[(b-b0)*9216+p][256] bf16 --------
__global__ void __launch_bounds__(256, 2)
k_xt(const float* __restrict__ x, unsigned short* __restrict__ xt, int b0) {
  __shared__ short Lt[64][72];
  const int tid = threadIdx.x;
  const int bid = blockIdx.x;        // NB * 576 (4 ct * 144 ptile per b)
  const int bb = bid / 576;
  const int r2 = bid - bb * 576;
  const int ct = r2 / 144;
  const int ptile = r2 - ct * 144;
  const int c0 = ct * 64, p0 = ptile * 64;
  const float* xb = x + ((size_t)((b0 + bb) * 256 + c0)) * 9216 + p0;
#pragma unroll
  for (int i = 0; i < 16; ++i) {
    int idx = i * 256 + tid;
    int c = idx >> 6, p = idx & 63;
    Lt[c][p] = (short)f2b(xb[(size_t)c * 9216 + p]);
  }
  __syncthreads();
  unsigned short* xto = xt + ((size_t)bb * 9216 + p0) * 256 + c0;
#pragma unroll
  for (int i = 0; i < 2; ++i) {
    int t = i * 256 + tid;             // 0..511
    int p = t & 63, oc = t >> 6;       // oc 0..7
    bf16x8 v8;
#pragma unroll
    for (int e = 0; e < 8; ++e) v8[e] = Lt[oc * 8 + e][p];
    *(bf16x8*)&xto[(size_t)p * 256 + oc * 8] = v8;
  }
}

// ---------------- k_qkv: dense GEMM qkv[p][o] = xt[p][c] @ W^T, streaming --------
// Block: 128o x 128p, K=256. Both operands direct from global (L2). 4 waves 2x2.
__global__ void __launch_bounds__(256, 4)
k_qkv(const unsigned short* __restrict__ w_bf, const unsigned short* __restrict__ xt,
      unsigned short* __restrict__ qkv) {
  const int tid = threadIdx.x;
  const int N = gridDim.x;           // NB*432, %8==0
  const int lg = (blockIdx.x & 7) * (N >> 3) + (blockIdx.x >> 3);
  const int pt = lg / 6;             // 6 consecutive logicals share p-tile (XCD L2)
  const int ot = lg - pt * 6;
  const int o0 = ot * 128;
  const int wv = tid >> 6, lane = tid & 63, ln = lane & 15, qq = lane >> 4;
  const int ow = (wv >> 1) * 64, pw = (wv & 1) * 64;
  const size_t prow = (size_t)pt * 128 + pw;   // chunk-local p row (72 tiles per b)
  const unsigned short* xbase = xt + (prow + ln) * 256;
  const unsigned short* wbase = w_bf + (size_t)(o0 + ow + ln) * 256;

  f32x4 acc[4][4];
#pragma unroll
  for (int mf = 0; mf < 4; ++mf)
#pragma unroll
    for (int nf = 0; nf < 4; ++nf) acc[mf][nf] = {0.f, 0.f, 0.f, 0.f};

  for (int ks = 0; ks < 8; ++ks) {
    const int co = ks * 32 + qq * 8;
    bf16x8 bfr[4], afr[4];
#pragma unroll
    for (int nf = 0; nf < 4; ++nf) bfr[nf] = *(const bf16x8*)&xbase[(size_t)nf * 4096 + co];
#pragma unroll
    for (int mf = 0; mf < 4; ++mf) afr[mf] = *(const bf16x8*)&wbase[(size_t)mf * 4096 + co];
#pragma unroll
    for (int mf = 0; mf < 4; ++mf)
#pragma unroll
      for (int nf = 0; nf < 4; ++nf)
        acc[mf][nf] = __builtin_amdgcn_mfma_f32_16x16x32_bf16(afr[mf], bfr[nf], acc[mf][nf], 0, 0, 0);
  }
#pragma unroll
  for (int mf = 0; mf < 4; ++mf)
#pragma unroll
    for (int nf = 0; nf < 4; ++nf) {
      bf16x4 sv;
#pragma unroll
      for (int r = 0; r < 4; ++r) sv[r] = (short)f2b(acc[mf][nf][r]);
      *(bf16x4*)&qkv[(prow + nf * 16 + ln) * 768 + o0 + ow + mf * 16 + qq * 4] = sv;
    }
}

// ---------------- k_attn: per-window 10-token attention + LN/GELU ----------------
// Block: 2 windows, 4 waves; wave -> grp = wv>>1, heads (wv&1)*4+tt. q/k fragments
// gathered direct from qkv (L2); v staged to LDS (swizzled, 2-way-free writes).
__global__ void __launch_bounds__(256, 3)
k_attn(const unsigned short* __restrict__ qkv, const unsigned short* __restrict__ tok_b,
       const float* __restrict__ ln_g, const float* __restrict__ ln_b,
       unsigned short* __restrict__ t_b, unsigned short* __restrict__ gf_t, int b0) {
  __shared__ __align__(16) short smem[23040];   // vt[512][40] @0, pl[4][16][40] @20480
  short* vt = smem;
  short* pl = smem + 20480;

  const int tid = threadIdx.x;
  const int N = gridDim.x;            // NB*512, %8==0
  const int lg = (blockIdx.x & 7) * (N >> 3) + (blockIdx.x >> 3);
  const int bb = lg >> 9;             // chunk-local b
  const int b  = b0 + bb;
  const int n0 = (lg & 511) * 2;
  const int wv = tid >> 6, lane = tid & 63, ln = lane & 15, qq = lane >> 4;
  const int grp = wv >> 1;
  const int n = n0 + grp;
  const size_t brow = (size_t)bb * 9216;

  // zero vt + pl (cols >=10 of vt and >=16 of pl must be zero)
  {
    bf16x8 z8 = {0, 0, 0, 0, 0, 0, 0, 0};
    for (int i = 0; i < 12; ++i) {
      int off = (i * 256 + tid) * 8;
      if (off < 23040) *(bf16x8*)&smem[off] = z8;
    }
  }
  __syncthreads();

  // stage V^T: vt[(win<<8)+d][j], j=0 token, j=1..9 pixels
  for (int it = 0; it < 9; ++it) {
    int t = it * 256 + tid;
    if (t < 2304) {
      int win = t >= 1152 ? 1 : 0;
      int rem = t - win * 1152;
      int pix = rem >> 7, dp = rem & 127, d = dp * 2;
      int nn = n0 + win;
      int gx = nn >> 5, gy = nn & 31;
      int gi = (pix * 11) >> 5, gj = pix - 3 * gi;
      int p = (gx * 3 + gi) * 96 + gy * 3 + gj;
      unsigned int u = *(const unsigned int*)&qkv[(brow + p) * 768 + 512 + d];
      int col = pix + 1;
      int r0 = (win << 8) + d;
      vt[r0 * 40 + swc(r0, col)] = (short)(u & 0xffffu);
      vt[(r0 + 1) * 40 + swc(r0 + 1, col)] = (short)(u >> 16);
    }
  }
#pragma unroll
  for (int i = 0; i < 2; ++i) {       // token v -> col 0
    int t = i * 256 + tid;            // row = (win<<8)+d = t
    vt[t * 40 + swc(t, 0)] = (short)tok_b[512 + (t & 255)];
  }
  __syncthreads();

  // per-lane q/k row pointer (row index within window = ln)
  const unsigned short* rowq;
  {
    bool isPix = (ln >= 1 && ln <= 9);
    int pix = ln - 1;
    int gi = isPix ? ((pix * 11) >> 5) : 0;
    int gj = isPix ? (pix - 3 * gi) : 0;
    int gx = n >> 5, gy = n & 31;
    int p = (gx * 3 + gi) * 96 + gy * 3 + gj;
    rowq = isPix ? qkv + (brow + p) * 768 + qq * 8 : tok_b + qq * 8;
  }

  f32x4 z = {0.f, 0.f, 0.f, 0.f};
  for (int tt = 0; tt < 4; ++tt) {
    int hh = (wv & 1) * 4 + tt;
    bf16x8 aq = *(const bf16x8*)&rowq[hh * 32];
    bf16x8 bk = *(const bf16x8*)&rowq[256 + hh * 32];
    f32x4 s = __builtin_amdgcn_mfma_f32_16x16x32_bf16(aq, bk, z, 0, 0, 0);

    float pr[4], sm[4];
#pragma unroll
    for (int r = 0; r < 4; ++r) {
      float sv = s[r] * kScale;
      if (ln >= 10) sv = -1e30f;
      float mx = sv;
#pragma unroll
      for (int d = 1; d < 16; d <<= 1) mx = fmaxf(mx, __shfl_xor(mx, d));
      pr[r] = __expf(sv - mx);
      float t2 = pr[r];
#pragma unroll
      for (int d = 1; d < 16; d <<= 1) t2 += __shfl_xor(t2, d);
      sm[r] = t2;
    }
#pragma unroll
    for (int r = 0; r < 4; ++r)
      pl[wv * 640 + (qq * 4 + r) * 40 + ln] = (short)f2b(pr[r]);

    bf16x8 ap = *(const bf16x8*)&pl[wv * 640 + ln * 40 + qq * 8];
    int rv0 = (grp << 8) + hh * 32 + ln;
    int rv1 = rv0 + 16;
    bf16x8 v0 = *(const bf16x8*)&vt[rv0 * 40 + swc(rv0, qq * 8)];
    bf16x8 v1 = *(const bf16x8*)&vt[rv1 * 40 + swc(rv1, qq * 8)];
    f32x4 o0 = __builtin_amdgcn_mfma_f32_16x16x32_bf16(ap, v0, z, 0, 0, 0);
    f32x4 o1 = __builtin_amdgcn_mfma_f32_16x16x32_bf16(ap, v1, z, 0, 0, 0);

    if (qq == 0) {  // row 0 = group token -> LN + GELU -> t
      float inv0 = 1.f / sm[0];
      float va = o0[0] * inv0, vb = o1[0] * inv0;
      float ssum = va + vb;
#pragma unroll
      for (int d = 1; d < 16; d <<= 1) ssum += __shfl_xor(ssum, d);
      float mu = ssum * (1.f / 32.f);
      float dva = va - mu, dvb = vb - mu;
      float vsum = dva * dva + dvb * dvb;
#pragma unroll
      for (int d = 1; d < 16; d <<= 1) vsum += __shfl_xor(vsum, d);
      float ri = rsqrtf(vsum * (1.f / 32.f) + 1e-5f);
      float g0 = dva * ri * ln_g[ln] + ln_b[ln];
      float g1 = dvb * ri * ln_g[16 + ln] + ln_b[16 + ln];
      float e0 = 0.5f * g0 * (1.f + erff(g0 * 0.70710678118654752f));
      float e1 = 0.5f * g1 * (1.f + erff(g1 * 0.70710678118654752f));
      size_t tb = ((size_t)(b * 1024 + n)) * 256 + hh * 32 + ln;
      t_b[tb] = f2b(e0);
      t_b[tb + 16] = f2b(e1);
    }
#pragma unroll
    for (int r = 0; r < 4; ++r) {
      int i = qq * 4 + r;
      if (i >= 1 && i <= 9) {
        float inv = 1.f / sm[r];
        size_t base = ((size_t)((b * 8 + hh) * 288) + (i - 1) * 32 + ln) * 1024 + n;
        gf_t[base] = f2b(o0[r] * inv);
        gf_t[base + 16 * 1024] = f2b(o1[r] * inv);
      }
    }
  }
}

// ---------------- k2: qk = w_qk(512x256) @ t + b_qk -> wq_b (scaled), wk_b ------
__global__ void __launch_bounds__(256, 2)
k_qk(const unsigned short* __restrict__ t_b, const float* __restrict__ w_qk,
     const float* __restrict__ b_qk, unsigned short* __restrict__ wq_b,
     unsigned short* __restrict__ wk_b) {
  __shared__ float t_l[128][33];
  __shared__ float w_l[64][33];
  int tid = threadIdx.x;
  int bid = blockIdx.x;       // 16 b * 8 h * 8 ntiles
  int b = bid >> 6;
  int h = (bid >> 3) & 7;
  int nt = bid & 7;
  int n_base = nt * 128;
  int te = tid & 15, tn = tid >> 4;
  float accq[4][8] = {};
  for (int c0 = 0; c0 < 256; c0 += 32) {
    for (int i = 0; i < 16; ++i) {
      int nl = i * 8 + (tid >> 5);
      t_l[nl][tid & 31] = b2f(t_b[((size_t)(b * kNG) + n_base + nl) * 256 + c0 + (tid & 31)]);
    }
    for (int i = 0; i < 8; ++i) {
      int e = i * 8 + (tid >> 5);
      w_l[e][tid & 31] = w_qk[(size_t)(h * 64 + e) * 256 + c0 + (tid & 31)];
    }
    __syncthreads();
    for (int cc = 0; cc < 32; ++cc) {
      float wvv[4], tvv[8];
#pragma unroll
      for (int i = 0; i < 4; ++i) wvv[i] = w_l[te + 16 * i][cc];
#pragma unroll
      for (int j = 0; j < 8; ++j) tvv[j] = t_l[tn + 16 * j][cc];
#pragma unroll
      for (int i = 0; i < 4; ++i)
#pragma unroll
        for (int j = 0; j < 8; ++j) accq[i][j] += wvv[i] * tvv[j];
    }
    __syncthreads();
  }
#pragma unroll
  for (int i = 0; i < 4; ++i) {
    int e = te + 16 * i;
    float bias = b_qk[h * 64 + e];
#pragma unroll
    for (int j = 0; j < 8; ++j) {
      int n = n_base + tn + 16 * j;
      float v = accq[i][j] + bias;
      size_t idx = (((size_t)b * kNH + h) * kNG + n) * 32;
      if (e < 32) wq_b[idx + e] = f2b(v * kScale);
      else        wk_b[idx + (e - 32)] = f2b(v);
    }
  }
}

// ---------------- k3: MFMA flash attention over gf_t (pre-transposed V) ---------
__global__ void __launch_bounds__(256, 3)
k_flash(const unsigned short* __restrict__ wq_b, const unsigned short* __restrict__ wk_b,
        const unsigned short* __restrict__ gf_t, unsigned short* __restrict__ agg_b) {
  __shared__ __align__(16) short vt[12800];   // [320][40] V^T: vt[d][j]
  __shared__ __align__(16) short pl[2560];    // [64][40]  P
  __shared__ float al_l[64];
  __shared__ float lrow_l[64];

  const int tid = threadIdx.x;
  const int bid0 = blockIdx.x;   // 128 bh * 16 qtiles
  const int xcd = bid0 & 7;
  const int s   = bid0 >> 3;
  const int bh  = xcd + 8 * (s >> 4);
  const int qt  = s & 15;
  const int wv = tid >> 6;
  const int lane = tid & 63;
  const int ln = lane & 15;
  const int qq = lane >> 4;
  const int d0 = wv * 80;

  bf16x8 aq = *(const bf16x8*)&wq_b[(size_t)(bh * 1024 + qt * 64 + wv * 16 + ln) * 32 + qq * 8];

  f32x4 accv[4][5];
  float mrow[4], lrow[4];
#pragma unroll
  for (int mf = 0; mf < 4; ++mf)
#pragma unroll
    for (int nf = 0; nf < 5; ++nf) accv[mf][nf] = {0.f, 0.f, 0.f, 0.f};
#pragma unroll
  for (int r = 0; r < 4; ++r) { mrow[r] = -1e30f; lrow[r] = 0.f; }

  for (int i = tid; i < 1280; i += 256) vt[11520 + i] = 0;

  for (int kt = 0; kt < 32; ++kt) {
    __syncthreads();
#pragma unroll
    for (int ii = 0; ii < 5; ++ii) {
      int i = ii * 256 + tid;
      if (i < 1152) {
        int d = i >> 2, c = (i & 3) * 8;
        bf16x8 g = *(const bf16x8*)&gf_t[((size_t)(bh * 288 + d)) * 1024 + kt * 32 + c];
        *(bf16x8*)&vt[d * 40 + c] = g;
      }
    }
    f32x4 z = {0.f, 0.f, 0.f, 0.f};
    bf16x8 kf0 = *(const bf16x8*)&wk_b[(size_t)(bh * 1024 + kt * 32 + ln) * 32 + qq * 8];
    bf16x8 kf1 = *(const bf16x8*)&wk_b[(size_t)(bh * 1024 + kt * 32 + 16 + ln) * 32 + qq * 8];
    f32x4 s0v = __builtin_amdgcn_mfma_f32_16x16x32_bf16(aq, kf0, z, 0, 0, 0);
    f32x4 s1v = __builtin_amdgcn_mfma_f32_16x16x32_bf16(aq, kf1, z, 0, 0, 0);
#pragma unroll
    for (int r = 0; r < 4; ++r) {
      float a0 = s0v[r], a1 = s1v[r];
      float tm = fmaxf(a0, a1);
#pragma unroll
      for (int d = 1; d < 16; d <<= 1) tm = fmaxf(tm, __shfl_xor(tm, d));
      float nm = fmaxf(mrow[r], tm);
      float al = __expf(mrow[r] - nm);
      mrow[r] = nm;
      float p0 = __expf(a0 - nm), p1 = __expf(a1 - nm);
      float ts = p0 + p1;
#pragma unroll
      for (int d = 1; d < 16; d <<= 1) ts += __shfl_xor(ts, d);
      lrow[r] = lrow[r] * al + ts;
      int row = wv * 16 + qq * 4 + r;
      pl[row * 40 + ln] = (short)f2b(p0);
      pl[row * 40 + 16 + ln] = (short)f2b(p1);
      if (ln == 0) al_l[row] = al;
    }
    __syncthreads();
#pragma unroll
    for (int mf = 0; mf < 4; ++mf)
#pragma unroll
      for (int r = 0; r < 4; ++r) {
        float alv = al_l[mf * 16 + qq * 4 + r];
#pragma unroll
        for (int nf = 0; nf < 5; ++nf) accv[mf][nf][r] *= alv;
      }
    bf16x8 ap[4];
#pragma unroll
    for (int mf = 0; mf < 4; ++mf)
      ap[mf] = *(const bf16x8*)&pl[(mf * 16 + ln) * 40 + qq * 8];
    __builtin_amdgcn_s_setprio(1);
#pragma unroll
    for (int nf = 0; nf < 5; ++nf) {
      bf16x8 vf = *(const bf16x8*)&vt[(d0 + nf * 16 + ln) * 40 + qq * 8];
#pragma unroll
      for (int mf = 0; mf < 4; ++mf)
        accv[mf][nf] = __builtin_amdgcn_mfma_f32_16x16x32_bf16(ap[mf], vf, accv[mf][nf], 0, 0, 0);
    }
    __builtin_amdgcn_s_setprio(0);
  }
#pragma unroll
  for (int r = 0; r < 4; ++r)
    if (ln == 0) lrow_l[wv * 16 + qq * 4 + r] = lrow[r];
  __syncthreads();
#pragma unroll
  for (int mf = 0; mf < 4; ++mf)
#pragma unroll
    for (int r = 0; r < 4; ++r) {
      float linv = 1.f / lrow_l[mf * 16 + qq * 4 + r];
      int row = qt * 64 + mf * 16 + qq * 4 + r;
#pragma unroll
      for (int nf = 0; nf < 5; ++nf) {
        int d = d0 + nf * 16 + ln;
        if (d < 288)
          agg_b[((size_t)(bh * 1024) + row) * 288 + d] = f2b(accv[mf][nf][r] * linv);
      }
    }
}

// ---------------- k4: out = w_out(256x256) @ fmap + b_out, MFMA version ----------
__global__ void __launch_bounds__(256, 2)
k_out(const unsigned short* __restrict__ agg_b,
      const unsigned short* __restrict__ w_hi, const unsigned short* __restrict__ w_lo,
      const float* __restrict__ b_out, float* __restrict__ out) {
  const int tid = threadIdx.x;
  const int bid = blockIdx.x;        // 16 b * 144 ptiles
  const int b = bid / 144;
  const int pt = bid - b * 144;
  const int p_base = pt * 64;
  const int wv = tid >> 6, lane = tid & 63, ln = lane & 15, qq = lane >> 4;
  const int obase = wv * 64;

  size_t vbase[4];
#pragma unroll
  for (int nf = 0; nf < 4; ++nf) {
    int p = p_base + nf * 16 + ln;
    int hh2 = p / 96, ww2 = p - hh2 * 96;
    int xg = hh2 / 3, gi = hh2 - xg * 3;
    int yg = ww2 / 3, gj = ww2 - yg * 3;
    int nn = xg * 32 + yg, w = gi * 3 + gj;
    vbase[nf] = ((size_t)b * 8 * 1024 + nn) * 288 + w * 32 + qq * 8;
  }

  f32x4 acc[4][4];
#pragma unroll
  for (int mf = 0; mf < 4; ++mf)
#pragma unroll
    for (int nf = 0; nf < 4; ++nf) acc[mf][nf] = {0.f, 0.f, 0.f, 0.f};

  for (int ks = 0; ks < 8; ++ks) {   // ks == h
    bf16x8 bfr[4];
#pragma unroll
    for (int nf = 0; nf < 4; ++nf)
      bfr[nf] = *(const bf16x8*)&agg_b[vbase[nf] + (size_t)ks * 294912];  // 1024*288
#pragma unroll
    for (int mf = 0; mf < 4; ++mf) {
      int o = obase + mf * 16 + ln;
      bf16x8 ah = *(const bf16x8*)&w_hi[o * 256 + ks * 32 + qq * 8];
      bf16x8 al = *(const bf16x8*)&w_lo[o * 256 + ks * 32 + qq * 8];
#pragma unroll
      for (int nf = 0; nf < 4; ++nf) {
        acc[mf][nf] = __builtin_amdgcn_mfma_f32_16x16x32_bf16(ah, bfr[nf], acc[mf][nf], 0, 0, 0);
        acc[mf][nf] = __builtin_amdgcn_mfma_f32_16x16x32_bf16(al, bfr[nf], acc[mf][nf], 0, 0, 0);
      }
    }
  }
#pragma unroll
  for (int mf = 0; mf < 4; ++mf) {
#pragma unroll
    for (int r = 0; r < 4; ++r) {
      int o = obase + mf * 16 + qq * 4 + r;
      float bias = b_out[o];
#pragma unroll
      for (int nf = 0; nf < 4; ++nf) {
        int p = p_base + nf * 16 + ln;
        out[((size_t)b * 256 + o) * 9216 + p] = acc[mf][nf][r] + bias;
      }
    }
  }
}

extern "C" void kernel_launch(void* const* d_in, const int* in_sizes, int n_in,
                              void* d_out, int out_size, void* d_ws, size_t ws_size,
                              hipStream_t stream) {
  const float* x     = (const float*)d_in[0];
  const float* w_qkv = (const float*)d_in[1];
  const float* gtok  = (const float*)d_in[2];
  const float* ln_g  = (const float*)d_in[3];
  const float* ln_b  = (const float*)d_in[4];
  const float* w_qk  = (const float*)d_in[5];
  const float* b_qk  = (const float*)d_in[6];
  const float* w_out = (const float*)d_in[7];
  const float* b_out = (const float*)d_in[8];
  float* out = (float*)d_out;

  // layout (shorts):
  unsigned short* ws   = (unsigned short*)d_ws;
  unsigned short* w_bf = ws;                        // 196,608
  unsigned short* w_hi = ws + 196608;               // 65,536
  unsigned short* w_lo = ws + 262144;               // 65,536
  unsigned short* tok  = ws + 327680;               // 768 (+pad)
  unsigned short* t_b  = ws + 328704;               // 4,194,304
  unsigned short* wq_b = ws + 4523008;              // 4,194,304
  unsigned short* wk_b = ws + 8717312;              // 4,194,304
  unsigned short* gf_t = ws + 12911616;             // 37,748,736
  unsigned short* R    = ws + 50660352;             // qkv+xt chunks, later agg

  // pick batch-chunk NB by available workspace
  auto need = [](int NBv) -> size_t {
    size_t reg = (size_t)NBv * 9437184ull;          // qkv + xt per chunk
    if (reg < 37748736ull) reg = 37748736ull;       // agg alias floor
    return (50660352ull + reg) * 2ull;
  };
  int NB = 4;                                       // worst case == old footprint
  if (ws_size >= need(16)) NB = 16;
  else if (ws_size >= need(8)) NB = 8;

  unsigned short* qkv = R;
  unsigned short* xt  = R + (size_t)NB * 7077888ull;
  unsigned short* agg_b = R;

  k_wcvt<<<1024, 256, 0, stream>>>(w_qkv, w_out, w_bf, w_hi, w_lo);
  k_tok<<<3, 256, 0, stream>>>(w_qkv, gtok, tok);
  for (int c = 0; c < 16 / NB; ++c) {
    int b0 = c * NB;
    k_xt<<<NB * 576, 256, 0, stream>>>(x, xt, b0);
    k_qkv<<<NB * 432, 256, 0, stream>>>(w_bf, xt, qkv);
    k_attn<<<NB * 512, 256, 0, stream>>>(qkv, tok, ln_g, ln_b, t_b, gf_t, b0);
  }
  k_qk<<<1024, 256, 0, stream>>>(t_b, w_qk, b_qk, wq_b, wk_b);
  k_flash<<<2048, 256, 0, stream>>>(wq_b, wk_b, gf_t, agg_b);
  k_out<<<2304, 256, 0, stream>>>(agg_b, w_hi, w_lo, b_out, out);
}